// Round 6
// baseline (119.331 us; speedup 1.0000x reference)
//
#include <hip/hip_runtime.h>

#define BETA_F 0.001f
constexpr int Bn = 8192, Dd = 1024, Kk = 2048, Ee = 512;

// ---------------------------------------------------------------------------
// Collapsed pipeline (validated R3-R5, absmax 0.0 every round):
//   m_e  = mean_k rec_w[e,k]
//   t_k  = BETA*( (2/E)*sum_e m_e*rec_w[e,k] - (1/E)*sum_e rec_w[e,k]^2 )
//   yp   = softmax_k(t)   (fp32 exact)
//   r*_d = sum_k yp_k * project_w[k,d]
//   loss_b = mean_d (r*_d - images[b,d])^2
// R5 post-mortem: top-5 = harness poison fills (~86 us, BW-bound, untouchable);
// our controllable part ~19 us. This round: drop OUR memset (partial-sum
// buffers written directly, no zero-init; rstar zeroed by stats block (0,0)),
// fuse row_mean into the stats kernel, 5 -> 4 dispatches, no fills from us.
// ---------------------------------------------------------------------------

__device__ __forceinline__ float blk_reduce_sum(float v) {
    #pragma unroll
    for (int off = 32; off > 0; off >>= 1) v += __shfl_xor(v, off);
    __shared__ float red[4];
    __syncthreads();
    if ((threadIdx.x & 63) == 0) red[threadIdx.x >> 6] = v;
    __syncthreads();
    return (red[0] + red[1]) + (red[2] + red[3]);
}

// Fused row-mean + column partial stats over rec_w (E,K).
// grid (2, 32): blockIdx.x = k-half, blockIdx.y = 16-row group.
// Each block reads its 16 rows in FULL (128 KB) to get the row means in-block
// (no separate row_mean kernel, no inter-kernel dependency), then emits its
// half-row of tm/tsq partials with direct float4 stores (no atomics, no
// pre-zeroed buffers). Block (0,0) also zeroes rstar (consumed 2 kernels later).
__global__ __launch_bounds__(256) void stats_fused(
    const float* __restrict__ w,
    float* __restrict__ tm_part,    // (32, K)
    float* __restrict__ tsq_part,   // (32, K)
    float* __restrict__ rstar)      // (D) — zeroed here
{
    const int t = threadIdx.x;
    const int kh = blockIdx.x;            // 0..1
    const int eb = blockIdx.y;            // 0..31
    const int e0 = eb * 16;
    const float4* wp = (const float4*)w;  // (E, K/4 = 512)
    const int k4 = kh * 256 + t;          // my float4 column
    const int o4 = (1 - kh) * 256 + t;    // other-half column (mean only)

    __shared__ float m_acc[16];
    if (t < 16) m_acc[t] = 0.f;
    __syncthreads();

    float4 vs[16];
    #pragma unroll
    for (int j = 0; j < 16; j++)
        vs[j] = wp[(size_t)(e0 + j) * (Kk / 4) + k4];

    float p[16];
    #pragma unroll
    for (int j = 0; j < 16; j++)
        p[j] = (vs[j].x + vs[j].y) + (vs[j].z + vs[j].w);
    // other half, two 8-deep batches (caps VGPR while keeping 8 loads in flight)
    #pragma unroll
    for (int b = 0; b < 2; b++) {
        float4 ov[8];
        #pragma unroll
        for (int j = 0; j < 8; j++)
            ov[j] = wp[(size_t)(e0 + b * 8 + j) * (Kk / 4) + o4];
        #pragma unroll
        for (int j = 0; j < 8; j++)
            p[b * 8 + j] += (ov[j].x + ov[j].y) + (ov[j].z + ov[j].w);
    }
    // per-row wave reduce -> LDS atomic (4 adds per row)
    #pragma unroll
    for (int j = 0; j < 16; j++) {
        float s = p[j];
        #pragma unroll
        for (int off = 32; off > 0; off >>= 1) s += __shfl_xor(s, off);
        if ((t & 63) == 0) atomicAdd(&m_acc[j], s);
    }
    __syncthreads();

    float4 sm = {0.f, 0.f, 0.f, 0.f}, sq = {0.f, 0.f, 0.f, 0.f};
    #pragma unroll
    for (int j = 0; j < 16; j++) {
        float mv = m_acc[j] * (1.f / (float)Kk);
        sm.x += mv * vs[j].x; sm.y += mv * vs[j].y;
        sm.z += mv * vs[j].z; sm.w += mv * vs[j].w;
        sq.x += vs[j].x * vs[j].x; sq.y += vs[j].y * vs[j].y;
        sq.z += vs[j].z * vs[j].z; sq.w += vs[j].w * vs[j].w;
    }
    ((float4*)(tm_part  + (size_t)eb * Kk))[k4] = sm;
    ((float4*)(tsq_part + (size_t)eb * Kk))[k4] = sq;

    if (kh == 0 && eb == 0) {
        float4 z = {0.f, 0.f, 0.f, 0.f};
        ((float4*)rstar)[t] = z;          // 256 x 16B = 1024 floats
    }
}

// tvec[k] = BETA*((2/E)*sum_eb tm_part - (1/E)*sum_eb tsq_part). grid 8 x 256.
__global__ __launch_bounds__(256) void reduce_t(
    const float* __restrict__ tm_part, const float* __restrict__ tsq_part,
    float* __restrict__ tvec)
{
    int k = blockIdx.x * 256 + threadIdx.x;
    float tm = 0.f, ts = 0.f;
    #pragma unroll
    for (int eb = 0; eb < 32; eb++) {
        tm += tm_part[(size_t)eb * Kk + k];
        ts += tsq_part[(size_t)eb * Kk + k];
    }
    tvec[k] = BETA_F * ((2.f / (float)Ee) * tm - ts * (1.f / (float)Ee));
}

// softmax (|t|<1e-5: no max-subtraction needed) + rstar accumulation.
// 256 blocks x 8 pw-rows; each block redundantly computes the denominator
// (8 expf/thread over K=2048 from the tiny L2-resident tvec).
__global__ __launch_bounds__(256) void rstar_softmax(
    const float* __restrict__ tvec, const float* __restrict__ pw,
    float* __restrict__ rstar)
{
    const int t = threadIdx.x;
    float s = 0.f;
    #pragma unroll
    for (int j = 0; j < 8; j++) s += __expf(tvec[t * 8 + j]);
    s = blk_reduce_sum(s);
    const float inv = 1.f / s;

    const int k0 = blockIdx.x * 8;
    const float4* pwp = (const float4*)pw;   // (K, D/4 = 256)
    float4 vs[8];
    #pragma unroll
    for (int j = 0; j < 8; j++)
        vs[j] = pwp[(size_t)(k0 + j) * (Dd / 4) + t];
    float4 acc = {0.f, 0.f, 0.f, 0.f};
    #pragma unroll
    for (int j = 0; j < 8; j++) {
        float wv = __expf(tvec[k0 + j]) * inv;
        acc.x += wv * vs[j].x; acc.y += wv * vs[j].y;
        acc.z += wv * vs[j].z; acc.w += wv * vs[j].w;
    }
    int d = t * 4;
    atomicAdd(&rstar[d + 0], acc.x); atomicAdd(&rstar[d + 1], acc.y);
    atomicAdd(&rstar[d + 2], acc.z); atomicAdd(&rstar[d + 3], acc.w);
}

// loss[b] = (1/D) * sum_d (rstar[d] - img[b,d])^2   (block per row, D=1024)
__global__ __launch_bounds__(256) void loss_rows(
    const float* __restrict__ img, const float* __restrict__ rstar,
    float* __restrict__ loss)
{
    size_t base = (size_t)blockIdx.x * Dd;
    float4 x = ((const float4*)(img + base))[threadIdx.x];
    float4 r = ((const float4*)rstar)[threadIdx.x];
    float dx = r.x - x.x, dy = r.y - x.y, dz = r.z - x.z, dw = r.w - x.w;
    float s = dx * dx + dy * dy + dz * dz + dw * dw;
    s = blk_reduce_sum(s);
    if (threadIdx.x == 0) loss[blockIdx.x] = s * (1.f / (float)Dd);
}

extern "C" void kernel_launch(void* const* d_in, const int* in_sizes, int n_in,
                              void* d_out, int out_size, void* d_ws, size_t ws_size,
                              hipStream_t stream) {
    const float* images    = (const float*)d_in[0];   // (B, D)
    const float* project_w = (const float*)d_in[1];   // (K, D)
    const float* rec_w     = (const float*)d_in[2];   // (E, K)
    float* loss_out = (float*)d_out;                  // (B,)

    // workspace: tm_part(32K) | tsq_part(32K) | rstar(D) | tvec(K)  (~520 KB)
    float* tm_part  = (float*)d_ws;
    float* tsq_part = tm_part + 32 * Kk;
    float* rstar    = tsq_part + 32 * Kk;
    float* tvec     = rstar + Dd;

    stats_fused<<<dim3(2, 32), 256, 0, stream>>>(rec_w, tm_part, tsq_part, rstar);
    reduce_t<<<Kk / 256, 256, 0, stream>>>(tm_part, tsq_part, tvec);
    rstar_softmax<<<Kk / 8, 256, 0, stream>>>(tvec, project_w, rstar);
    loss_rows<<<Bn, 256, 0, stream>>>(images, rstar, loss_out);
}

// Round 7
// 103.111 us; speedup vs baseline: 1.1573x; 1.1573x over previous
//
#include <hip/hip_runtime.h>

#define BETA_F 0.001f
constexpr int Bn = 8192, Dd = 1024, Kk = 2048, Ee = 512;

// ---------------------------------------------------------------------------
// Collapsed pipeline (validated R3-R6, absmax 0.0 every round):
//   m_e  = mean_k rec_w[e,k]
//   t_k  = BETA*( (2/E)*sum_e m_e*rec_w[e,k] - (1/E)*sum_e rec_w[e,k]^2 )
//   yp   = softmax_k(t)   (fp32 exact)
//   r*_d = sum_k yp_k * project_w[k,d]
//   loss_b = mean_d (r*_d - images[b,d])^2
// R6 post-mortem: 105 -> 119 us regression from (a) 64-block stats kernel with
// doubled row reads, (b) 2x atomic contention in rstar_softmax; top-5 in both
// rounds is harness poison fills (268 MB @ 76% HBM peak) we cannot touch.
// This round: measured-best R5 structure, minus our memset — col_stats writes
// partials directly (no atomics / no zero-init), reduce_t zeroes the 4 KB
// rstar. 5 dispatches, no fills issued by us.
// ---------------------------------------------------------------------------

__device__ __forceinline__ float blk_reduce_sum(float v) {
    #pragma unroll
    for (int off = 32; off > 0; off >>= 1) v += __shfl_xor(v, off);
    __shared__ float red[4];
    __syncthreads();
    if ((threadIdx.x & 63) == 0) red[threadIdx.x >> 6] = v;
    __syncthreads();
    return (red[0] + red[1]) + (red[2] + red[3]);
}

// m[e] = mean_k rec_w[e,k]   (block per row e; 256 thr x 2 float4 = 2048)
__global__ __launch_bounds__(256) void row_mean(
    const float* __restrict__ w, float* __restrict__ m)
{
    size_t base = (size_t)blockIdx.x * Kk;
    const float4* p = (const float4*)(w + base);
    float4 a = p[threadIdx.x];
    float4 b = p[threadIdx.x + 256];
    float s = (a.x + a.y + a.z + a.w) + (b.x + b.y + b.z + b.w);
    s = blk_reduce_sum(s);
    if (threadIdx.x == 0) m[blockIdx.x] = s * (1.f / (float)Kk);
}

// Column partial stats over a 16-row chunk of rec_w (E,K):
//   tm_part[eb][k] = sum_e m[e]*w[e,k],  tsq_part[eb][k] = sum_e w[e,k]^2
// grid (2, 32) = 64 blocks; thread owns 4 k's (float4); 16 batched dwordx4
// loads up-front (ILP — the R4 lesson). Direct stores: no atomics, no memset.
__global__ __launch_bounds__(256) void col_stats(
    const float* __restrict__ w, const float* __restrict__ m,
    float* __restrict__ tm_part, float* __restrict__ tsq_part)
{
    const int k4 = blockIdx.x * 256 + threadIdx.x;   // float4 column index
    const int eb = blockIdx.y;
    const int e0 = eb * 16;
    const float4* wp = (const float4*)w;             // (E, K/4)
    float4 vs[16];
    #pragma unroll
    for (int j = 0; j < 16; j++)
        vs[j] = wp[(size_t)(e0 + j) * (Kk / 4) + k4];
    float4 sm = {0.f, 0.f, 0.f, 0.f}, sq = {0.f, 0.f, 0.f, 0.f};
    #pragma unroll
    for (int j = 0; j < 16; j++) {
        float mv = m[e0 + j];                        // wave-uniform scalar load
        sm.x += mv * vs[j].x; sm.y += mv * vs[j].y;
        sm.z += mv * vs[j].z; sm.w += mv * vs[j].w;
        sq.x += vs[j].x * vs[j].x; sq.y += vs[j].y * vs[j].y;
        sq.z += vs[j].z * vs[j].z; sq.w += vs[j].w * vs[j].w;
    }
    ((float4*)(tm_part  + (size_t)eb * Kk))[k4] = sm;
    ((float4*)(tsq_part + (size_t)eb * Kk))[k4] = sq;
}

// tvec[k] = BETA*((2/E)*sum_eb tm_part - (1/E)*sum_eb tsq_part). grid 8 x 256.
// Block 0 also zeroes rstar (4 KB) — consumed by the NEXT dispatch (stream-
// ordered), replacing the hipMemsetAsync.
__global__ __launch_bounds__(256) void reduce_t(
    const float* __restrict__ tm_part, const float* __restrict__ tsq_part,
    float* __restrict__ tvec, float* __restrict__ rstar)
{
    int k = blockIdx.x * 256 + threadIdx.x;
    float tm = 0.f, ts = 0.f;
    #pragma unroll
    for (int eb = 0; eb < 32; eb++) {
        tm += tm_part[(size_t)eb * Kk + k];
        ts += tsq_part[(size_t)eb * Kk + k];
    }
    tvec[k] = BETA_F * ((2.f / (float)Ee) * tm - ts * (1.f / (float)Ee));
    if (blockIdx.x == 0) {
        float4 z = {0.f, 0.f, 0.f, 0.f};
        ((float4*)rstar)[threadIdx.x] = z;   // 256 x 16B = 1024 floats
    }
}

// softmax (|t|<1e-5: no max-subtraction needed) + rstar accumulation.
// R5's measured-best config: 128 blocks x 16 pw-rows; each block redundantly
// computes the denominator from the L2-resident 8 KB tvec, then accumulates
// its 16 rows of project_w into rstar (atomics, 128-way per address).
__global__ __launch_bounds__(256) void rstar_softmax(
    const float* __restrict__ tvec, const float* __restrict__ pw,
    float* __restrict__ rstar)
{
    const int t = threadIdx.x;
    float s = 0.f;
    #pragma unroll
    for (int j = 0; j < 8; j++) s += __expf(tvec[t * 8 + j]);
    s = blk_reduce_sum(s);
    const float inv = 1.f / s;

    const int k0 = blockIdx.x * 16;
    const float4* pwp = (const float4*)pw;   // (K, D/4 = 256)
    float4 vs[16];
    #pragma unroll
    for (int j = 0; j < 16; j++)
        vs[j] = pwp[(size_t)(k0 + j) * (Dd / 4) + t];
    float4 acc = {0.f, 0.f, 0.f, 0.f};
    #pragma unroll
    for (int j = 0; j < 16; j++) {
        float wv = __expf(tvec[k0 + j]) * inv;
        acc.x += wv * vs[j].x; acc.y += wv * vs[j].y;
        acc.z += wv * vs[j].z; acc.w += wv * vs[j].w;
    }
    int d = t * 4;
    atomicAdd(&rstar[d + 0], acc.x); atomicAdd(&rstar[d + 1], acc.y);
    atomicAdd(&rstar[d + 2], acc.z); atomicAdd(&rstar[d + 3], acc.w);
}

// loss[b] = (1/D) * sum_d (rstar[d] - img[b,d])^2   (block per row, D=1024)
__global__ __launch_bounds__(256) void loss_rows(
    const float* __restrict__ img, const float* __restrict__ rstar,
    float* __restrict__ loss)
{
    size_t base = (size_t)blockIdx.x * Dd;
    float4 x = ((const float4*)(img + base))[threadIdx.x];
    float4 r = ((const float4*)rstar)[threadIdx.x];
    float dx = r.x - x.x, dy = r.y - x.y, dz = r.z - x.z, dw = r.w - x.w;
    float s = dx * dx + dy * dy + dz * dz + dw * dw;
    s = blk_reduce_sum(s);
    if (threadIdx.x == 0) loss[blockIdx.x] = s * (1.f / (float)Dd);
}

extern "C" void kernel_launch(void* const* d_in, const int* in_sizes, int n_in,
                              void* d_out, int out_size, void* d_ws, size_t ws_size,
                              hipStream_t stream) {
    const float* images    = (const float*)d_in[0];   // (B, D)
    const float* project_w = (const float*)d_in[1];   // (K, D)
    const float* rec_w     = (const float*)d_in[2];   // (E, K)
    float* loss_out = (float*)d_out;                  // (B,)

    // workspace: tm_part(32K) | tsq_part(32K) | rstar(D) | tvec(K) | m(E)
    float* tm_part  = (float*)d_ws;
    float* tsq_part = tm_part + 32 * Kk;
    float* rstar    = tsq_part + 32 * Kk;
    float* tvec     = rstar + Dd;
    float* m        = tvec + Kk;

    row_mean<<<Ee, 256, 0, stream>>>(rec_w, m);
    col_stats<<<dim3(2, 32), 256, 0, stream>>>(rec_w, m, tm_part, tsq_part);
    reduce_t<<<Kk / 256, 256, 0, stream>>>(tm_part, tsq_part, tvec, rstar);
    rstar_softmax<<<Kk / 16, 256, 0, stream>>>(tvec, project_w, rstar);
    loss_rows<<<Bn, 256, 0, stream>>>(images, rstar, loss_out);
}